// Round 5
// baseline (1143.647 us; speedup 1.0000x reference)
//
#include <hip/hip_runtime.h>

typedef unsigned short ushort_t;
typedef __attribute__((ext_vector_type(8))) __bf16 bf16x8;
typedef __attribute__((ext_vector_type(4))) float f32x4;

#define N_ROWS 8192

// ---------- bf16 helpers (RNE, no hip_bf16 dependency) ----------
__device__ __forceinline__ ushort_t f2bf(float f) {
    unsigned int x;
    __builtin_memcpy(&x, &f, 4);
    unsigned int lsb = (x >> 16) & 1u;
    x += 0x7fffu + lsb;
    return (ushort_t)(x >> 16);
}
__device__ __forceinline__ float bf2f(ushort_t u) {
    unsigned int x = ((unsigned int)u) << 16;
    float f;
    __builtin_memcpy(&f, &x, 4);
    return f;
}

// Swizzled position of element (c=col, j=row/contraction idx) in the transposed,
// per-64k-chunk B layout. 16B unit index within a chunk: c*8 + (k8 ^ (c&7)).
__device__ __forceinline__ size_t bofs(int c, int j, int W) {
    int kc = j >> 6;
    int k8 = (j >> 3) & 7;
    int kr = j & 7;
    return (size_t)kc * (size_t)(W * 64) + (size_t)((c * 8 + (k8 ^ (c & 7))) * 8 + kr);
}

// ---------- setup: d = rsqrt(diag(D)) for both graphs, zero xsum ----------
__global__ void setup_k(const float* __restrict__ D1, const float* __restrict__ D2,
                        float* __restrict__ dout, float* __restrict__ xsum) {
    int gid = blockIdx.x * 256 + threadIdx.x;
    if (gid < 16384) {
        int g = gid >> 13, row = gid & 8191;
        const float* D = g ? D2 : D1;
        dout[gid] = rsqrtf(D[(size_t)row * (N_ROWS + 1)]);
    }
    if (gid < 32) xsum[gid] = 0.f;
}

// ---------- prep1: B1 = d .* (H @ W1) -> split bf16, swizzled transposed ----------
__global__ void prep1_k(const float* __restrict__ H1, const float* __restrict__ H2,
                        const float* __restrict__ W1, const float* __restrict__ dall,
                        ushort_t* __restrict__ Bh, ushort_t* __restrict__ Bl) {
    int g = blockIdx.z;
    const float* H = g ? H2 : H1;
    const float* dd = dall + g * N_ROWS;
    ushort_t* bh = Bh + (size_t)g * N_ROWS * 64;
    ushort_t* bl = Bl + (size_t)g * N_ROWS * 64;
    int c = threadIdx.x & 63;
    int jj = threadIdx.x >> 6;
    int j = blockIdx.x * 4 + jj;
    float acc = 0.f;
    for (int m = 0; m < 128; m++)
        acc += H[(size_t)j * 128 + m] * W1[m * 64 + c];
    float val = dd[j] * acc;
    ushort_t h = f2bf(val);
    ushort_t l = f2bf(val - bf2f(h));
    size_t pos = bofs(c, j, 64);
    bh[pos] = h;
    bl[pos] = l;
}

// ---------- prep (layers 2/3): B = d .* (relu(d .* sum_kz T) @ Wm) ----------
template <int MIN, int WOUT>
__global__ void prep_k(const float* __restrict__ T, const float* __restrict__ Wm,
                       const float* __restrict__ dall,
                       ushort_t* __restrict__ Bh, ushort_t* __restrict__ Bl) {
    int g = blockIdx.z;
    const size_t S = (size_t)N_ROWS * MIN;
    const float* Tp = T + (size_t)g * 4 * S;
    const float* dd = dall + g * N_ROWS;
    ushort_t* bh = Bh + (size_t)g * N_ROWS * WOUT;
    ushort_t* bl = Bl + (size_t)g * N_ROWS * WOUT;
    constexpr int JPB = 256 / WOUT;
    int c = threadIdx.x & (WOUT - 1);
    int jj = threadIdx.x / WOUT;
    int j = blockIdx.x * JPB + jj;
    float dj = dd[j];
    float acc = 0.f;
    for (int m = 0; m < MIN; m++) {
        size_t o = (size_t)j * MIN + m;
        float ts = Tp[o] + Tp[S + o] + Tp[2 * S + o] + Tp[3 * S + o];
        float x = fmaxf(dj * ts, 0.f);
        acc += x * Wm[m * WOUT + c];
    }
    float val = dj * acc;
    ushort_t h = f2bf(val);
    ushort_t l = f2bf(val - bf2f(h));
    size_t pos = bofs(c, j, WOUT);
    bh[pos] = h;
    bl[pos] = l;
}

// ---------- main GEMM: T[g][kz] = A[g] @ B[g] (raw partial sums, split-bf16 MFMA) ----------
// Register-double-buffered: tile kt+1's global loads are issued before tile kt is
// consumed, so HBM latency hides under convert+LDS+MFMA work.
template <int W>
__global__ __launch_bounds__(256, 2) void gemm_k(const float* __restrict__ A1,
                                                 const float* __restrict__ A2,
                                                 const ushort_t* __restrict__ Bth,
                                                 const ushort_t* __restrict__ Btl,
                                                 float* __restrict__ T) {
    constexpr int BM = 128, KP = 72, CT = W / 16;
    constexpr int NB = (W * 8 + 255) / 256;  // 16B-chunks per thread for B copy
    __shared__ ushort_t Ah[BM * KP];
    __shared__ ushort_t Al[BM * KP];
    __shared__ ushort_t Bh[W * 64];
    __shared__ ushort_t Bl[W * 64];

    int g = blockIdx.z, kz = blockIdx.y;
    const float* A = g ? A2 : A1;
    const ushort_t* bth = Bth + (size_t)g * N_ROWS * W;
    const ushort_t* btl = Btl + (size_t)g * N_ROWS * W;
    float* Tout = T + ((size_t)g * 4 + kz) * (size_t)N_ROWS * W;

    int t = threadIdx.x;
    int lane = t & 63, wave = t >> 6;
    int lrow = lane & 15, quad = lane >> 4;
    int block_row = blockIdx.x * BM;
    int f4 = t & 15, r0 = t >> 4;

    f32x4 acc[2][CT];
    const f32x4 zero4 = {0.f, 0.f, 0.f, 0.f};
#pragma unroll
    for (int rt = 0; rt < 2; rt++)
#pragma unroll
        for (int ct = 0; ct < CT; ct++) acc[rt][ct] = zero4;

    const float* Abase = A + (size_t)(block_row + r0) * N_ROWS + f4 * 4;

    // two named register sets (no runtime-indexed buffers -> no scratch)
    float4 avA[8], avB[8];
    int4 bhA[NB], blA[NB], bhB[NB], blB[NB];

#define LOAD_TILE(av_, bh_, bl_, kt_)                                          \
    {                                                                          \
        int k0_ = kz * 2048 + (kt_) * 64;                                      \
        const float* Ak_ = Abase + k0_;                                        \
        _Pragma("unroll") for (int i = 0; i < 8; i++)                          \
            av_[i] = *(const float4*)(Ak_ + (size_t)i * 16 * N_ROWS);          \
        const int4* sh_ = (const int4*)(bth + (size_t)(k0_ >> 6) * (W * 64));  \
        const int4* sl_ = (const int4*)(btl + (size_t)(k0_ >> 6) * (W * 64));  \
        _Pragma("unroll") for (int i = 0; i < NB; i++) {                       \
            int idx_ = t + i * 256;                                            \
            if (idx_ < W * 8) { bh_[i] = sh_[idx_]; bl_[i] = sl_[idx_]; }      \
        }                                                                      \
    }

#define PROCESS_TILE(av_, bh_, bl_)                                            \
    {                                                                          \
        __syncthreads(); /* previous iteration's LDS reads complete */         \
        _Pragma("unroll") for (int i = 0; i < NB; i++) {                       \
            int idx_ = t + i * 256;                                            \
            if (idx_ < W * 8) {                                                \
                ((int4*)Bh)[idx_] = bh_[i];                                    \
                ((int4*)Bl)[idx_] = bl_[i];                                    \
            }                                                                  \
        }                                                                      \
        _Pragma("unroll") for (int i = 0; i < 8; i++) {                        \
            int row_ = r0 + 16 * i;                                            \
            float4 v_ = av_[i];                                                \
            ushort4 hh_, ll_;                                                  \
            hh_.x = f2bf(v_.x); ll_.x = f2bf(v_.x - bf2f(hh_.x));              \
            hh_.y = f2bf(v_.y); ll_.y = f2bf(v_.y - bf2f(hh_.y));              \
            hh_.z = f2bf(v_.z); ll_.z = f2bf(v_.z - bf2f(hh_.z));              \
            hh_.w = f2bf(v_.w); ll_.w = f2bf(v_.w - bf2f(hh_.w));              \
            *(ushort4*)&Ah[row_ * KP + f4 * 4] = hh_;                          \
            *(ushort4*)&Al[row_ * KP + f4 * 4] = ll_;                          \
        }                                                                      \
        __syncthreads();                                                       \
        _Pragma("unroll") for (int s = 0; s < 2; s++) {                        \
            bf16x8 a_h_[2], a_l_[2];                                           \
            _Pragma("unroll") for (int rt = 0; rt < 2; rt++) {                 \
                int off_ = (wave * 32 + rt * 16 + lrow) * KP + s * 32 + quad * 8; \
                a_h_[rt] = *(const bf16x8*)&Ah[off_];                          \
                a_l_[rt] = *(const bf16x8*)&Al[off_];                          \
            }                                                                  \
            _Pragma("unroll") for (int ct = 0; ct < CT; ct++) {                \
                int col_ = ct * 16 + lrow;                                     \
                int u_ = col_ * 8 + ((s * 4 + quad) ^ (col_ & 7));             \
                bf16x8 b_h_ = *(const bf16x8*)&Bh[u_ * 8];                     \
                bf16x8 b_l_ = *(const bf16x8*)&Bl[u_ * 8];                     \
                _Pragma("unroll") for (int rt = 0; rt < 2; rt++) {             \
                    acc[rt][ct] = __builtin_amdgcn_mfma_f32_16x16x32_bf16(a_h_[rt], b_h_, acc[rt][ct], 0, 0, 0); \
                    acc[rt][ct] = __builtin_amdgcn_mfma_f32_16x16x32_bf16(a_h_[rt], b_l_, acc[rt][ct], 0, 0, 0); \
                    acc[rt][ct] = __builtin_amdgcn_mfma_f32_16x16x32_bf16(a_l_[rt], b_h_, acc[rt][ct], 0, 0, 0); \
                }                                                              \
            }                                                                  \
        }                                                                      \
    }

    LOAD_TILE(avA, bhA, blA, 0);
#pragma unroll 1
    for (int kt = 0; kt < 32; kt += 2) {
        // prefetch kt+1 while consuming kt
        LOAD_TILE(avB, bhB, blB, kt + 1);
        PROCESS_TILE(avA, bhA, blA);
        // prefetch kt+2 (wrap on last iter; result unused) while consuming kt+1
        int ktn = (kt + 2 < 32) ? (kt + 2) : 0;
        LOAD_TILE(avA, bhA, blA, ktn);
        PROCESS_TILE(avB, bhB, blB);
    }
#undef LOAD_TILE
#undef PROCESS_TILE

    // ---- epilogue: raw partial sums (C/D layout: col=lane&15, row=quad*4+v) ----
#pragma unroll
    for (int rt = 0; rt < 2; rt++)
#pragma unroll
        for (int ct = 0; ct < CT; ct++)
#pragma unroll
            for (int v = 0; v < 4; v++) {
                int grow = block_row + wave * 32 + rt * 16 + quad * 4 + v;
                int col = ct * 16 + lrow;
                Tout[(size_t)grow * W + col] = acc[rt][ct][v];
            }
}

// ---------- column mean of relu(d .* sum_kz T3) -> xsum (x16 per graph) ----------
__global__ void meanred_k(const float* __restrict__ T3, const float* __restrict__ dall,
                          float* __restrict__ xsum) {
    int g = blockIdx.z;
    const size_t S = (size_t)N_ROWS * 16;
    const float* Tp = T3 + (size_t)g * 4 * S;
    const float* dd = dall + g * N_ROWS;
    int t = threadIdx.x;
    int c = t & 15, jr = t >> 4;
    float sum = 0.f;
    for (int i = 0; i < 8; i++) {
        int j = blockIdx.x * 128 + jr + 16 * i;
        size_t o = (size_t)j * 16 + c;
        float v = Tp[o] + Tp[S + o] + Tp[2 * S + o] + Tp[3 * S + o];
        sum += fmaxf(dd[j] * v, 0.f);
    }
    __shared__ float red[256];
    red[t] = sum;
    __syncthreads();
    if (t < 16) {
        float tot = 0.f;
        for (int k = 0; k < 16; k++) tot += red[t + k * 16];
        atomicAdd(&xsum[g * 16 + t], tot);
    }
}

// ---------- combine + tiny MLP -> scalar ----------
__global__ void combine_k(const float* __restrict__ xsum, const float* __restrict__ cw1,
                          const float* __restrict__ cw2, const float* __restrict__ cbias,
                          const float* __restrict__ fw1, const float* __restrict__ fb1,
                          const float* __restrict__ fw2, const float* __restrict__ fb2,
                          const float* __restrict__ fw3, const float* __restrict__ fb3,
                          float* __restrict__ out) {
    __shared__ float x[16], y[16], z[16];
    int t = threadIdx.x;
    if (t < 16) x[t] = xsum[t] * (1.0f / 8192.0f);
    else if (t < 32) y[t - 16] = xsum[t] * (1.0f / 8192.0f);
    __syncthreads();
    if (t < 16) {
        float r = 0.f;
        for (int i = 0; i < 16; i++)
            for (int j = 0; j < 16; j++)
                r += x[i] * cw1[(i * 16 + j) * 16 + t] * y[j];
        float p = 0.f;
        for (int m = 0; m < 16; m++) p += cw2[t * 32 + m] * x[m];
        for (int m = 0; m < 16; m++) p += cw2[t * 32 + 16 + m] * y[m];
        z[t] = fmaxf(r + p + cbias[t], 0.f);
    }
    __syncthreads();
    if (t == 0) {
        float h1[8], h2[4];
        for (int a = 0; a < 8; a++) {
            float s = fb1[a];
            for (int k = 0; k < 16; k++) s += z[k] * fw1[a * 16 + k];
            h1[a] = fmaxf(s, 0.f);
        }
        for (int b = 0; b < 4; b++) {
            float s = fb2[b];
            for (int a = 0; a < 8; a++) s += h1[a] * fw2[b * 8 + a];
            h2[b] = fmaxf(s, 0.f);
        }
        float s = fb3[0];
        for (int b = 0; b < 4; b++) s += h2[b] * fw3[b];
        out[0] = fmaxf(s, 0.f);
    }
}

extern "C" void kernel_launch(void* const* d_in, const int* in_sizes, int n_in,
                              void* d_out, int out_size, void* d_ws, size_t ws_size,
                              hipStream_t stream) {
    const float* A1 = (const float*)d_in[0];
    const float* D1 = (const float*)d_in[1];
    const float* H1 = (const float*)d_in[2];
    const float* A2 = (const float*)d_in[3];
    const float* D2 = (const float*)d_in[4];
    const float* H2 = (const float*)d_in[5];
    const float* W1 = (const float*)d_in[6];
    const float* W2 = (const float*)d_in[7];
    const float* W3 = (const float*)d_in[8];
    const float* cw1 = (const float*)d_in[9];
    const float* cw2 = (const float*)d_in[10];
    const float* cbias = (const float*)d_in[11];
    const float* fw1 = (const float*)d_in[12];
    const float* fb1 = (const float*)d_in[13];
    const float* fw2 = (const float*)d_in[14];
    const float* fb2 = (const float*)d_in[15];
    const float* fw3 = (const float*)d_in[16];
    const float* fb3 = (const float*)d_in[17];

    float* ws = (float*)d_ws;
    float* dv = ws;                                   // 2*8192 floats
    float* xsum = ws + 16384;                         // 32 floats (+pad to 16448)
    float* T1 = ws + 16448;                           // [2][4][8192][64]
    float* T2 = T1 + (size_t)2 * 4 * 8192 * 64;       // [2][4][8192][32]
    float* T3 = T2 + (size_t)2 * 4 * 8192 * 32;       // [2][4][8192][16]
    ushort_t* B1h = (ushort_t*)(T3 + (size_t)2 * 4 * 8192 * 16);
    ushort_t* B1l = B1h + (size_t)2 * 8192 * 64;
    ushort_t* B2h = B1l + (size_t)2 * 8192 * 64;
    ushort_t* B2l = B2h + (size_t)2 * 8192 * 32;
    ushort_t* B3h = B2l + (size_t)2 * 8192 * 32;
    ushort_t* B3l = B3h + (size_t)2 * 8192 * 16;

    hipLaunchKernelGGL(setup_k, dim3(64), dim3(256), 0, stream, D1, D2, dv, xsum);
    hipLaunchKernelGGL(prep1_k, dim3(2048, 1, 2), dim3(256), 0, stream, H1, H2, W1, dv, B1h, B1l);
    hipLaunchKernelGGL((gemm_k<64>), dim3(64, 4, 2), dim3(256), 0, stream, A1, A2, B1h, B1l, T1);
    hipLaunchKernelGGL((prep_k<64, 32>), dim3(1024, 1, 2), dim3(256), 0, stream, T1, W2, dv, B2h, B2l);
    hipLaunchKernelGGL((gemm_k<32>), dim3(64, 4, 2), dim3(256), 0, stream, A1, A2, B2h, B2l, T2);
    hipLaunchKernelGGL((prep_k<32, 16>), dim3(512, 1, 2), dim3(256), 0, stream, T2, W3, dv, B3h, B3l);
    hipLaunchKernelGGL((gemm_k<16>), dim3(64, 4, 2), dim3(256), 0, stream, A1, A2, B3h, B3l, T3);
    hipLaunchKernelGGL(meanred_k, dim3(64, 1, 2), dim3(256), 0, stream, T3, dv, xsum);
    hipLaunchKernelGGL(combine_k, dim3(1), dim3(64), 0, stream, xsum, cw1, cw2, cbias,
                       fw1, fb1, fw2, fb2, fw3, fb3, (float*)d_out);
}

// Round 6
// 1142.311 us; speedup vs baseline: 1.0012x; 1.0012x over previous
//
#include <hip/hip_runtime.h>

typedef unsigned short ushort_t;
typedef __attribute__((ext_vector_type(8))) __bf16 bf16x8;
typedef __attribute__((ext_vector_type(4))) float f32x4;

#define N_ROWS 8192

// ---------- bf16 helpers (RNE, no hip_bf16 dependency) ----------
__device__ __forceinline__ ushort_t f2bf(float f) {
    unsigned int x;
    __builtin_memcpy(&x, &f, 4);
    unsigned int lsb = (x >> 16) & 1u;
    x += 0x7fffu + lsb;
    return (ushort_t)(x >> 16);
}
__device__ __forceinline__ float bf2f(ushort_t u) {
    unsigned int x = ((unsigned int)u) << 16;
    float f;
    __builtin_memcpy(&f, &x, 4);
    return f;
}

// Swizzled position of element (c=col, j=row/contraction idx) in the transposed,
// per-64k-chunk B layout. 16B unit index within a chunk: c*8 + (k8 ^ (c&7)).
__device__ __forceinline__ size_t bofs(int c, int j, int W) {
    int kc = j >> 6;
    int k8 = (j >> 3) & 7;
    int kr = j & 7;
    return (size_t)kc * (size_t)(W * 64) + (size_t)((c * 8 + (k8 ^ (c & 7))) * 8 + kr);
}

// ---------- setup: d = rsqrt(diag(D)) for both graphs, zero xsum ----------
__global__ void setup_k(const float* __restrict__ D1, const float* __restrict__ D2,
                        float* __restrict__ dout, float* __restrict__ xsum) {
    int gid = blockIdx.x * 256 + threadIdx.x;
    if (gid < 16384) {
        int g = gid >> 13, row = gid & 8191;
        const float* D = g ? D2 : D1;
        dout[gid] = rsqrtf(D[(size_t)row * (N_ROWS + 1)]);
    }
    if (gid < 32) xsum[gid] = 0.f;
}

// ---------- prep1: B1 = d .* (H @ W1) -> split bf16, swizzled transposed ----------
__global__ void prep1_k(const float* __restrict__ H1, const float* __restrict__ H2,
                        const float* __restrict__ W1, const float* __restrict__ dall,
                        ushort_t* __restrict__ Bh, ushort_t* __restrict__ Bl) {
    int g = blockIdx.z;
    const float* H = g ? H2 : H1;
    const float* dd = dall + g * N_ROWS;
    ushort_t* bh = Bh + (size_t)g * N_ROWS * 64;
    ushort_t* bl = Bl + (size_t)g * N_ROWS * 64;
    int c = threadIdx.x & 63;
    int jj = threadIdx.x >> 6;
    int j = blockIdx.x * 4 + jj;
    float acc = 0.f;
    for (int m = 0; m < 128; m++)
        acc += H[(size_t)j * 128 + m] * W1[m * 64 + c];
    float val = dd[j] * acc;
    ushort_t h = f2bf(val);
    ushort_t l = f2bf(val - bf2f(h));
    size_t pos = bofs(c, j, 64);
    bh[pos] = h;
    bl[pos] = l;
}

// ---------- prep (layers 2/3): B = d .* (relu(d .* sum_kz T) @ Wm) ----------
template <int MIN, int WOUT>
__global__ void prep_k(const float* __restrict__ T, const float* __restrict__ Wm,
                       const float* __restrict__ dall,
                       ushort_t* __restrict__ Bh, ushort_t* __restrict__ Bl) {
    int g = blockIdx.z;
    const size_t S = (size_t)N_ROWS * MIN;
    const float* Tp = T + (size_t)g * 4 * S;
    const float* dd = dall + g * N_ROWS;
    ushort_t* bh = Bh + (size_t)g * N_ROWS * WOUT;
    ushort_t* bl = Bl + (size_t)g * N_ROWS * WOUT;
    constexpr int JPB = 256 / WOUT;
    int c = threadIdx.x & (WOUT - 1);
    int jj = threadIdx.x / WOUT;
    int j = blockIdx.x * JPB + jj;
    float dj = dd[j];
    float acc = 0.f;
    for (int m = 0; m < MIN; m++) {
        size_t o = (size_t)j * MIN + m;
        float ts = Tp[o] + Tp[S + o] + Tp[2 * S + o] + Tp[3 * S + o];
        float x = fmaxf(dj * ts, 0.f);
        acc += x * Wm[m * WOUT + c];
    }
    float val = dj * acc;
    ushort_t h = f2bf(val);
    ushort_t l = f2bf(val - bf2f(h));
    size_t pos = bofs(c, j, WOUT);
    bh[pos] = h;
    bl[pos] = l;
}

// ---------- main GEMM: T[g][kz] = A[g] @ B[g] (raw partial sums, split-bf16 MFMA) ----------
// Register-double-buffered: tile kt+1's global loads are issued before tile kt is
// consumed, so HBM latency hides under convert+LDS+MFMA work.
// amdgpu_waves_per_eu(2,2): occupancy is LDS-capped at 2 blocks/CU anyway; telling
// the allocator the ceiling lets it use the full 256-VGPR budget instead of
// spilling the prefetch buffers to scratch (R5: VGPR=68, WRITE_SIZE=280MB).
template <int W>
__global__ __attribute__((amdgpu_waves_per_eu(2, 2)))
__launch_bounds__(256) void gemm_k(const float* __restrict__ A1,
                                   const float* __restrict__ A2,
                                   const ushort_t* __restrict__ Bth,
                                   const ushort_t* __restrict__ Btl,
                                   float* __restrict__ T) {
    constexpr int BM = 128, KP = 72, CT = W / 16;
    constexpr int NB = (W * 8 + 255) / 256;  // 16B-chunks per thread for B copy
    __shared__ ushort_t Ah[BM * KP];
    __shared__ ushort_t Al[BM * KP];
    __shared__ ushort_t Bh[W * 64];
    __shared__ ushort_t Bl[W * 64];

    int g = blockIdx.z, kz = blockIdx.y;
    const float* A = g ? A2 : A1;
    const ushort_t* bth = Bth + (size_t)g * N_ROWS * W;
    const ushort_t* btl = Btl + (size_t)g * N_ROWS * W;
    float* Tout = T + ((size_t)g * 4 + kz) * (size_t)N_ROWS * W;

    int t = threadIdx.x;
    int lane = t & 63, wave = t >> 6;
    int lrow = lane & 15, quad = lane >> 4;
    int block_row = blockIdx.x * BM;
    int f4 = t & 15, r0 = t >> 4;

    f32x4 acc[2][CT];
    const f32x4 zero4 = {0.f, 0.f, 0.f, 0.f};
#pragma unroll
    for (int rt = 0; rt < 2; rt++)
#pragma unroll
        for (int ct = 0; ct < CT; ct++) acc[rt][ct] = zero4;

    const float* Abase = A + (size_t)(block_row + r0) * N_ROWS + f4 * 4;

    // two named register sets (no runtime-indexed buffers -> no scratch)
    float4 avA[8], avB[8];
    int4 bhA[NB], blA[NB], bhB[NB], blB[NB];

#define LOAD_TILE(av_, bh_, bl_, kt_)                                          \
    {                                                                          \
        int k0_ = kz * 2048 + (kt_) * 64;                                      \
        const float* Ak_ = Abase + k0_;                                        \
        _Pragma("unroll") for (int i = 0; i < 8; i++)                          \
            av_[i] = *(const float4*)(Ak_ + (size_t)i * 16 * N_ROWS);          \
        const int4* sh_ = (const int4*)(bth + (size_t)(k0_ >> 6) * (W * 64));  \
        const int4* sl_ = (const int4*)(btl + (size_t)(k0_ >> 6) * (W * 64));  \
        _Pragma("unroll") for (int i = 0; i < NB; i++) {                       \
            int idx_ = t + i * 256;                                            \
            if (idx_ < W * 8) { bh_[i] = sh_[idx_]; bl_[i] = sl_[idx_]; }      \
        }                                                                      \
    }

#define PROCESS_TILE(av_, bh_, bl_)                                            \
    {                                                                          \
        __syncthreads(); /* previous iteration's LDS reads complete */         \
        _Pragma("unroll") for (int i = 0; i < NB; i++) {                       \
            int idx_ = t + i * 256;                                            \
            if (idx_ < W * 8) {                                                \
                ((int4*)Bh)[idx_] = bh_[i];                                    \
                ((int4*)Bl)[idx_] = bl_[i];                                    \
            }                                                                  \
        }                                                                      \
        _Pragma("unroll") for (int i = 0; i < 8; i++) {                        \
            int row_ = r0 + 16 * i;                                            \
            float4 v_ = av_[i];                                                \
            ushort4 hh_, ll_;                                                  \
            hh_.x = f2bf(v_.x); ll_.x = f2bf(v_.x - bf2f(hh_.x));              \
            hh_.y = f2bf(v_.y); ll_.y = f2bf(v_.y - bf2f(hh_.y));              \
            hh_.z = f2bf(v_.z); ll_.z = f2bf(v_.z - bf2f(hh_.z));              \
            hh_.w = f2bf(v_.w); ll_.w = f2bf(v_.w - bf2f(hh_.w));              \
            *(ushort4*)&Ah[row_ * KP + f4 * 4] = hh_;                          \
            *(ushort4*)&Al[row_ * KP + f4 * 4] = ll_;                          \
        }                                                                      \
        __syncthreads();                                                       \
        _Pragma("unroll") for (int s = 0; s < 2; s++) {                        \
            bf16x8 a_h_[2], a_l_[2];                                           \
            _Pragma("unroll") for (int rt = 0; rt < 2; rt++) {                 \
                int off_ = (wave * 32 + rt * 16 + lrow) * KP + s * 32 + quad * 8; \
                a_h_[rt] = *(const bf16x8*)&Ah[off_];                          \
                a_l_[rt] = *(const bf16x8*)&Al[off_];                          \
            }                                                                  \
            _Pragma("unroll") for (int ct = 0; ct < CT; ct++) {                \
                int col_ = ct * 16 + lrow;                                     \
                int u_ = col_ * 8 + ((s * 4 + quad) ^ (col_ & 7));             \
                bf16x8 b_h_ = *(const bf16x8*)&Bh[u_ * 8];                     \
                bf16x8 b_l_ = *(const bf16x8*)&Bl[u_ * 8];                     \
                _Pragma("unroll") for (int rt = 0; rt < 2; rt++) {             \
                    acc[rt][ct] = __builtin_amdgcn_mfma_f32_16x16x32_bf16(a_h_[rt], b_h_, acc[rt][ct], 0, 0, 0); \
                    acc[rt][ct] = __builtin_amdgcn_mfma_f32_16x16x32_bf16(a_h_[rt], b_l_, acc[rt][ct], 0, 0, 0); \
                    acc[rt][ct] = __builtin_amdgcn_mfma_f32_16x16x32_bf16(a_l_[rt], b_h_, acc[rt][ct], 0, 0, 0); \
                }                                                              \
            }                                                                  \
        }                                                                      \
    }

    LOAD_TILE(avA, bhA, blA, 0);
#pragma unroll 1
    for (int kt = 0; kt < 32; kt += 2) {
        // prefetch kt+1 while consuming kt
        LOAD_TILE(avB, bhB, blB, kt + 1);
        PROCESS_TILE(avA, bhA, blA);
        // prefetch kt+2 (wrap on last iter; result unused) while consuming kt+1
        int ktn = (kt + 2 < 32) ? (kt + 2) : 0;
        LOAD_TILE(avA, bhA, blA, ktn);
        PROCESS_TILE(avB, bhB, blB);
    }
#undef LOAD_TILE
#undef PROCESS_TILE

    // ---- epilogue: raw partial sums (C/D layout: col=lane&15, row=quad*4+v) ----
#pragma unroll
    for (int rt = 0; rt < 2; rt++)
#pragma unroll
        for (int ct = 0; ct < CT; ct++)
#pragma unroll
            for (int v = 0; v < 4; v++) {
                int grow = block_row + wave * 32 + rt * 16 + quad * 4 + v;
                int col = ct * 16 + lrow;
                Tout[(size_t)grow * W + col] = acc[rt][ct][v];
            }
}

// ---------- column mean of relu(d .* sum_kz T3) -> xsum (x16 per graph) ----------
__global__ void meanred_k(const float* __restrict__ T3, const float* __restrict__ dall,
                          float* __restrict__ xsum) {
    int g = blockIdx.z;
    const size_t S = (size_t)N_ROWS * 16;
    const float* Tp = T3 + (size_t)g * 4 * S;
    const float* dd = dall + g * N_ROWS;
    int t = threadIdx.x;
    int c = t & 15, jr = t >> 4;
    float sum = 0.f;
    for (int i = 0; i < 8; i++) {
        int j = blockIdx.x * 128 + jr + 16 * i;
        size_t o = (size_t)j * 16 + c;
        float v = Tp[o] + Tp[S + o] + Tp[2 * S + o] + Tp[3 * S + o];
        sum += fmaxf(dd[j] * v, 0.f);
    }
    __shared__ float red[256];
    red[t] = sum;
    __syncthreads();
    if (t < 16) {
        float tot = 0.f;
        for (int k = 0; k < 16; k++) tot += red[t + k * 16];
        atomicAdd(&xsum[g * 16 + t], tot);
    }
}

// ---------- combine + tiny MLP -> scalar ----------
__global__ void combine_k(const float* __restrict__ xsum, const float* __restrict__ cw1,
                          const float* __restrict__ cw2, const float* __restrict__ cbias,
                          const float* __restrict__ fw1, const float* __restrict__ fb1,
                          const float* __restrict__ fw2, const float* __restrict__ fb2,
                          const float* __restrict__ fw3, const float* __restrict__ fb3,
                          float* __restrict__ out) {
    __shared__ float x[16], y[16], z[16];
    int t = threadIdx.x;
    if (t < 16) x[t] = xsum[t] * (1.0f / 8192.0f);
    else if (t < 32) y[t - 16] = xsum[t] * (1.0f / 8192.0f);
    __syncthreads();
    if (t < 16) {
        float r = 0.f;
        for (int i = 0; i < 16; i++)
            for (int j = 0; j < 16; j++)
                r += x[i] * cw1[(i * 16 + j) * 16 + t] * y[j];
        float p = 0.f;
        for (int m = 0; m < 16; m++) p += cw2[t * 32 + m] * x[m];
        for (int m = 0; m < 16; m++) p += cw2[t * 32 + 16 + m] * y[m];
        z[t] = fmaxf(r + p + cbias[t], 0.f);
    }
    __syncthreads();
    if (t == 0) {
        float h1[8], h2[4];
        for (int a = 0; a < 8; a++) {
            float s = fb1[a];
            for (int k = 0; k < 16; k++) s += z[k] * fw1[a * 16 + k];
            h1[a] = fmaxf(s, 0.f);
        }
        for (int b = 0; b < 4; b++) {
            float s = fb2[b];
            for (int a = 0; a < 8; a++) s += h1[a] * fw2[b * 8 + a];
            h2[b] = fmaxf(s, 0.f);
        }
        float s = fb3[0];
        for (int b = 0; b < 4; b++) s += h2[b] * fw3[b];
        out[0] = fmaxf(s, 0.f);
    }
}

extern "C" void kernel_launch(void* const* d_in, const int* in_sizes, int n_in,
                              void* d_out, int out_size, void* d_ws, size_t ws_size,
                              hipStream_t stream) {
    const float* A1 = (const float*)d_in[0];
    const float* D1 = (const float*)d_in[1];
    const float* H1 = (const float*)d_in[2];
    const float* A2 = (const float*)d_in[3];
    const float* D2 = (const float*)d_in[4];
    const float* H2 = (const float*)d_in[5];
    const float* W1 = (const float*)d_in[6];
    const float* W2 = (const float*)d_in[7];
    const float* W3 = (const float*)d_in[8];
    const float* cw1 = (const float*)d_in[9];
    const float* cw2 = (const float*)d_in[10];
    const float* cbias = (const float*)d_in[11];
    const float* fw1 = (const float*)d_in[12];
    const float* fb1 = (const float*)d_in[13];
    const float* fw2 = (const float*)d_in[14];
    const float* fb2 = (const float*)d_in[15];
    const float* fw3 = (const float*)d_in[16];
    const float* fb3 = (const float*)d_in[17];

    float* ws = (float*)d_ws;
    float* dv = ws;                                   // 2*8192 floats
    float* xsum = ws + 16384;                         // 32 floats (+pad to 16448)
    float* T1 = ws + 16448;                           // [2][4][8192][64]
    float* T2 = T1 + (size_t)2 * 4 * 8192 * 64;       // [2][4][8192][32]
    float* T3 = T2 + (size_t)2 * 4 * 8192 * 32;       // [2][4][8192][16]
    ushort_t* B1h = (ushort_t*)(T3 + (size_t)2 * 4 * 8192 * 16);
    ushort_t* B1l = B1h + (size_t)2 * 8192 * 64;
    ushort_t* B2h = B1l + (size_t)2 * 8192 * 64;
    ushort_t* B2l = B2h + (size_t)2 * 8192 * 32;
    ushort_t* B3h = B2l + (size_t)2 * 8192 * 32;
    ushort_t* B3l = B3h + (size_t)2 * 8192 * 16;

    hipLaunchKernelGGL(setup_k, dim3(64), dim3(256), 0, stream, D1, D2, dv, xsum);
    hipLaunchKernelGGL(prep1_k, dim3(2048, 1, 2), dim3(256), 0, stream, H1, H2, W1, dv, B1h, B1l);
    hipLaunchKernelGGL((gemm_k<64>), dim3(64, 4, 2), dim3(256), 0, stream, A1, A2, B1h, B1l, T1);
    hipLaunchKernelGGL((prep_k<64, 32>), dim3(1024, 1, 2), dim3(256), 0, stream, T1, W2, dv, B2h, B2l);
    hipLaunchKernelGGL((gemm_k<32>), dim3(64, 4, 2), dim3(256), 0, stream, A1, A2, B2h, B2l, T2);
    hipLaunchKernelGGL((prep_k<32, 16>), dim3(512, 1, 2), dim3(256), 0, stream, T2, W3, dv, B3h, B3l);
    hipLaunchKernelGGL((gemm_k<16>), dim3(64, 4, 2), dim3(256), 0, stream, A1, A2, B3h, B3l, T3);
    hipLaunchKernelGGL(meanred_k, dim3(64, 1, 2), dim3(256), 0, stream, T3, dv, xsum);
    hipLaunchKernelGGL(combine_k, dim3(1), dim3(64), 0, stream, xsum, cw1, cw2, cbias,
                       fw1, fb1, fw2, fb2, fw3, fb3, (float*)d_out);
}